// Round 1
// baseline (1229.570 us; speedup 1.0000x reference)
//
#include <hip/hip_runtime.h>
#include <math.h>

#define F 128
#define TILE_R 64
#define NTHREADS 256

// acc[c] += sum_i xv[i] * w[i][c]   (4 k-steps, 4 cols)
__device__ __forceinline__ void fma_step(float4& acc, const float4 xv, const float4* w) {
    acc.x = fmaf(xv.x, w[0].x, acc.x); acc.x = fmaf(xv.y, w[1].x, acc.x);
    acc.x = fmaf(xv.z, w[2].x, acc.x); acc.x = fmaf(xv.w, w[3].x, acc.x);
    acc.y = fmaf(xv.x, w[0].y, acc.y); acc.y = fmaf(xv.y, w[1].y, acc.y);
    acc.y = fmaf(xv.z, w[2].y, acc.y); acc.y = fmaf(xv.w, w[3].y, acc.y);
    acc.z = fmaf(xv.x, w[0].z, acc.z); acc.z = fmaf(xv.y, w[1].z, acc.z);
    acc.z = fmaf(xv.z, w[2].z, acc.z); acc.z = fmaf(xv.w, w[3].z, acc.z);
    acc.w = fmaf(xv.x, w[0].w, acc.w); acc.w = fmaf(xv.y, w[1].w, acc.w);
    acc.w = fmaf(xv.z, w[2].w, acc.w); acc.w = fmaf(xv.w, w[3].w, acc.w);
}

// ---------------- Kernel 1: Ah = h@WA + bA, Bh = h@WB + bB ----------------
__global__ __launch_bounds__(NTHREADS)
void node_ab_kernel(const float* __restrict__ h,
                    const float* __restrict__ WA, const float* __restrict__ bA,
                    const float* __restrict__ WB, const float* __restrict__ bB,
                    float* __restrict__ Ah, float* __restrict__ Bh, int N)
{
    __shared__ float xs[TILE_R][F];           // 32 KB input tile
    const int t = threadIdx.x;
    const int row0 = blockIdx.x * TILE_R;

    for (int i = t; i < TILE_R * (F / 4); i += NTHREADS) {
        const int r = i >> 5;                 // F/4 == 32 float4 per row
        const int c4 = i & 31;
        float4 v = make_float4(0.f, 0.f, 0.f, 0.f);
        if (row0 + r < N) v = ((const float4*)(h + (size_t)(row0 + r) * F))[c4];
        ((float4*)xs[r])[c4] = v;
    }
    __syncthreads();

    const int cg = t & 31, rg = t >> 5;
    const int col = cg * 4;
    float4 accA[8], accB[8];
    #pragma unroll
    for (int r = 0; r < 8; ++r) {
        accA[r] = make_float4(0.f, 0.f, 0.f, 0.f);
        accB[r] = make_float4(0.f, 0.f, 0.f, 0.f);
    }

    for (int k = 0; k < F; k += 4) {
        float4 wa[4], wb[4];
        #pragma unroll
        for (int i = 0; i < 4; ++i) {
            wa[i] = *(const float4*)(WA + (size_t)(k + i) * F + col);
            wb[i] = *(const float4*)(WB + (size_t)(k + i) * F + col);
        }
        #pragma unroll
        for (int r = 0; r < 8; ++r) {
            const float4 xv = *(const float4*)&xs[rg * 8 + r][k];
            fma_step(accA[r], xv, wa);
            fma_step(accB[r], xv, wb);
        }
    }

    const float4 ba = *(const float4*)(bA + col);
    const float4 bb = *(const float4*)(bB + col);
    #pragma unroll
    for (int r = 0; r < 8; ++r) {
        const int row = row0 + rg * 8 + r;
        if (row < N) {
            float4 va = accA[r];
            va.x += ba.x; va.y += ba.y; va.z += ba.z; va.w += ba.w;
            float4 vb = accB[r];
            vb.x += bb.x; vb.y += bb.y; vb.z += bb.z; vb.w += bb.w;
            *(float4*)(Ah + (size_t)row * F + col) = va;
            *(float4*)(Bh + (size_t)row * F + col) = vb;
        }
    }
}

// ------- Kernel 2: Ce GEMM + e_ij + e_out + gated message + scatter-max -------
__global__ __launch_bounds__(NTHREADS)
void edge_kernel(const float* __restrict__ e,
                 const int* __restrict__ src, const int* __restrict__ dst,
                 const float* __restrict__ WC, const float* __restrict__ bC,
                 const float* __restrict__ Ah, const float* __restrict__ Bh,
                 float* __restrict__ e_out, unsigned int* __restrict__ cbuf, int E)
{
    __shared__ float xs[TILE_R][F];           // 32 KB edge-feature tile
    const int t = threadIdx.x;
    const int row0 = blockIdx.x * TILE_R;

    for (int i = t; i < TILE_R * (F / 4); i += NTHREADS) {
        const int r = i >> 5;
        const int c4 = i & 31;
        float4 v = make_float4(0.f, 0.f, 0.f, 0.f);
        if (row0 + r < E) v = ((const float4*)(e + (size_t)(row0 + r) * F))[c4];
        ((float4*)xs[r])[c4] = v;
    }
    __syncthreads();

    const int cg = t & 31, rg = t >> 5;
    const int col = cg * 4;
    float4 acc[8];
    #pragma unroll
    for (int r = 0; r < 8; ++r) acc[r] = make_float4(0.f, 0.f, 0.f, 0.f);

    for (int k = 0; k < F; k += 4) {
        float4 wc[4];
        #pragma unroll
        for (int i = 0; i < 4; ++i)
            wc[i] = *(const float4*)(WC + (size_t)(k + i) * F + col);
        #pragma unroll
        for (int r = 0; r < 8; ++r) {
            const float4 xv = *(const float4*)&xs[rg * 8 + r][k];
            fma_step(acc[r], xv, wc);
        }
    }

    const float4 bc = *(const float4*)(bC + col);
    #pragma unroll
    for (int r = 0; r < 8; ++r) {
        const int ed = row0 + rg * 8 + r;
        if (ed < E) {
            const int s = src[ed], d = dst[ed];
            const float4 bhs = *(const float4*)(Bh + (size_t)s * F + col);
            const float4 bhd = *(const float4*)(Bh + (size_t)d * F + col);
            const float4 ahs = *(const float4*)(Ah + (size_t)s * F + col);
            float4 eij;
            eij.x = acc[r].x + bc.x + bhs.x + bhd.x;
            eij.y = acc[r].y + bc.y + bhs.y + bhd.y;
            eij.z = acc[r].z + bc.z + bhs.z + bhd.z;
            eij.w = acc[r].w + bc.w + bhs.w + bhd.w;

            const float4 ein = *(const float4*)&xs[rg * 8 + r][col];
            float4 eo;
            eo.x = ein.x + fmaxf(eij.x, 0.f);
            eo.y = ein.y + fmaxf(eij.y, 0.f);
            eo.z = ein.z + fmaxf(eij.z, 0.f);
            eo.w = ein.w + fmaxf(eij.w, 0.f);
            *(float4*)(e_out + (size_t)ed * F + col) = eo;

            // m = relu(sigmoid(e_ij) * Ah[src]); ternary forces +0 so the
            // uint bit-pattern max stays monotone (avoid -0.0 = 0x80000000).
            float m0 = ahs.x / (1.f + __expf(-eij.x)); m0 = (m0 > 0.f) ? m0 : 0.f;
            float m1 = ahs.y / (1.f + __expf(-eij.y)); m1 = (m1 > 0.f) ? m1 : 0.f;
            float m2 = ahs.z / (1.f + __expf(-eij.z)); m2 = (m2 > 0.f) ? m2 : 0.f;
            float m3 = ahs.w / (1.f + __expf(-eij.w)); m3 = (m3 > 0.f) ? m3 : 0.f;

            unsigned int* cb = cbuf + (size_t)d * F + col;
            atomicMax(cb + 0, __float_as_uint(m0));
            atomicMax(cb + 1, __float_as_uint(m1));
            atomicMax(cb + 2, __float_as_uint(m2));
            atomicMax(cb + 3, __float_as_uint(m3));
        }
    }
}

// ------- Kernel 3: bundle = [h,c]@Wap + bap; L2-normalize; relu; +h -------
__global__ __launch_bounds__(NTHREADS)
void apply_kernel(const float* __restrict__ h, const float* __restrict__ cbuf,
                  const float* __restrict__ Wap, const float* __restrict__ bap,
                  float* __restrict__ h_out, int N)
{
    __shared__ float xs[TILE_R][2 * F];       // 64 KB concat tile
    const int t = threadIdx.x;
    const int row0 = blockIdx.x * TILE_R;

    for (int i = t; i < TILE_R * (F / 4); i += NTHREADS) {
        const int r = i >> 5;
        const int c4 = i & 31;
        float4 hv = make_float4(0.f, 0.f, 0.f, 0.f);
        float4 cv = make_float4(0.f, 0.f, 0.f, 0.f);
        if (row0 + r < N) {
            hv = ((const float4*)(h + (size_t)(row0 + r) * F))[c4];
            cv = ((const float4*)(cbuf + (size_t)(row0 + r) * F))[c4];
        }
        ((float4*)xs[r])[c4] = hv;            // cols 0..127  : h
        ((float4*)xs[r])[c4 + 32] = cv;       // cols 128..255: c
    }
    __syncthreads();

    const int cg = t & 31, rg = t >> 5;
    const int col = cg * 4;
    float4 acc[8];
    #pragma unroll
    for (int r = 0; r < 8; ++r) acc[r] = make_float4(0.f, 0.f, 0.f, 0.f);

    for (int k = 0; k < 2 * F; k += 4) {
        float4 w[4];
        #pragma unroll
        for (int i = 0; i < 4; ++i)
            w[i] = *(const float4*)(Wap + (size_t)(k + i) * F + col);
        #pragma unroll
        for (int r = 0; r < 8; ++r) {
            const float4 xv = *(const float4*)&xs[rg * 8 + r][k];
            fma_step(acc[r], xv, w);
        }
    }

    const float4 bp = *(const float4*)(bap + col);
    #pragma unroll
    for (int r = 0; r < 8; ++r) {
        float4 a = acc[r];
        a.x += bp.x; a.y += bp.y; a.z += bp.z; a.w += bp.w;
        // row sum-of-squares: reduce over the 32 col-threads (half-wave)
        float ss = a.x * a.x + a.y * a.y + a.z * a.z + a.w * a.w;
        #pragma unroll
        for (int mm = 16; mm >= 1; mm >>= 1) ss += __shfl_xor(ss, mm, 64);
        const int row = row0 + rg * 8 + r;
        if (row < N) {
            const float dn = fmaxf(sqrtf(ss), 1e-12f);
            const float4 hv = *(const float4*)&xs[rg * 8 + r][col];
            float4 o;
            o.x = hv.x + fmaxf(a.x / dn, 0.f);
            o.y = hv.y + fmaxf(a.y / dn, 0.f);
            o.z = hv.z + fmaxf(a.z / dn, 0.f);
            o.w = hv.w + fmaxf(a.w / dn, 0.f);
            *(float4*)(h_out + (size_t)row * F + col) = o;
        }
    }
}

extern "C" void kernel_launch(void* const* d_in, const int* in_sizes, int n_in,
                              void* d_out, int out_size, void* d_ws, size_t ws_size,
                              hipStream_t stream)
{
    const float* h   = (const float*)d_in[0];
    const float* e   = (const float*)d_in[1];
    const int*   src = (const int*)d_in[2];
    const int*   dst = (const int*)d_in[3];
    const float* WA  = (const float*)d_in[4];
    const float* bA  = (const float*)d_in[5];
    const float* WB  = (const float*)d_in[6];
    const float* bB  = (const float*)d_in[7];
    const float* WC  = (const float*)d_in[8];
    const float* bC  = (const float*)d_in[9];
    const float* Wap = (const float*)d_in[10];
    const float* bap = (const float*)d_in[11];

    const int N = in_sizes[0] / F;
    const int E = in_sizes[2];

    float* Ah   = (float*)d_ws;                       // N*F
    float* Bh   = Ah + (size_t)N * F;                 // N*F
    float* cbuf = Bh + (size_t)N * F;                 // N*F (as uint bits)

    float* h_out = (float*)d_out;                     // N*F
    float* e_out = h_out + (size_t)N * F;             // E*F

    // segment-max identity: 0 bits == +0.0f (m >= 0 always; zero-degree -> 0)
    hipMemsetAsync(cbuf, 0, (size_t)N * F * sizeof(float), stream);

    const dim3 blk(NTHREADS);
    const int gn = (N + TILE_R - 1) / TILE_R;
    const int ge = (E + TILE_R - 1) / TILE_R;

    node_ab_kernel<<<gn, blk, 0, stream>>>(h, WA, bA, WB, bB, Ah, Bh, N);
    edge_kernel<<<ge, blk, 0, stream>>>(e, src, dst, WC, bC, Ah, Bh,
                                        e_out, (unsigned int*)cbuf, E);
    apply_kernel<<<gn, blk, 0, stream>>>(h, cbuf, Wap, bap, h_out, N);
}

// Round 3
// 994.405 us; speedup vs baseline: 1.2365x; 1.2365x over previous
//
#include <hip/hip_runtime.h>
#include <math.h>

#define F 128
#define TILE_R 64
#define NTHREADS 256

// acc[c] += sum_i xv[i] * w[i][c]   (4 k-steps, 4 cols)
__device__ __forceinline__ void fma_step(float4& acc, const float4 xv, const float4* w) {
    acc.x = fmaf(xv.x, w[0].x, acc.x); acc.x = fmaf(xv.y, w[1].x, acc.x);
    acc.x = fmaf(xv.z, w[2].x, acc.x); acc.x = fmaf(xv.w, w[3].x, acc.x);
    acc.y = fmaf(xv.x, w[0].y, acc.y); acc.y = fmaf(xv.y, w[1].y, acc.y);
    acc.y = fmaf(xv.z, w[2].y, acc.y); acc.y = fmaf(xv.w, w[3].y, acc.y);
    acc.z = fmaf(xv.x, w[0].z, acc.z); acc.z = fmaf(xv.y, w[1].z, acc.z);
    acc.z = fmaf(xv.z, w[2].z, acc.z); acc.z = fmaf(xv.w, w[3].z, acc.z);
    acc.w = fmaf(xv.x, w[0].w, acc.w); acc.w = fmaf(xv.y, w[1].w, acc.w);
    acc.w = fmaf(xv.z, w[2].w, acc.w); acc.w = fmaf(xv.w, w[3].w, acc.w);
}

// ---------------- Kernel 1: Ah = h@WA + bA, Bh = h@WB + bB ----------------
__global__ __launch_bounds__(NTHREADS)
void node_ab_kernel(const float* __restrict__ h,
                    const float* __restrict__ WA, const float* __restrict__ bA,
                    const float* __restrict__ WB, const float* __restrict__ bB,
                    float* __restrict__ Ah, float* __restrict__ Bh, int N)
{
    __shared__ float xs[TILE_R][F];           // 32 KB input tile
    const int t = threadIdx.x;
    const int row0 = blockIdx.x * TILE_R;

    for (int i = t; i < TILE_R * (F / 4); i += NTHREADS) {
        const int r = i >> 5;                 // F/4 == 32 float4 per row
        const int c4 = i & 31;
        float4 v = make_float4(0.f, 0.f, 0.f, 0.f);
        if (row0 + r < N) v = ((const float4*)(h + (size_t)(row0 + r) * F))[c4];
        ((float4*)xs[r])[c4] = v;
    }
    __syncthreads();

    const int cg = t & 31, rg = t >> 5;
    const int col = cg * 4;
    float4 accA[8], accB[8];
    #pragma unroll
    for (int r = 0; r < 8; ++r) {
        accA[r] = make_float4(0.f, 0.f, 0.f, 0.f);
        accB[r] = make_float4(0.f, 0.f, 0.f, 0.f);
    }

    for (int k = 0; k < F; k += 4) {
        float4 wa[4], wb[4];
        #pragma unroll
        for (int i = 0; i < 4; ++i) {
            wa[i] = *(const float4*)(WA + (size_t)(k + i) * F + col);
            wb[i] = *(const float4*)(WB + (size_t)(k + i) * F + col);
        }
        #pragma unroll
        for (int r = 0; r < 8; ++r) {
            const float4 xv = *(const float4*)&xs[rg * 8 + r][k];
            fma_step(accA[r], xv, wa);
            fma_step(accB[r], xv, wb);
        }
    }

    const float4 ba = *(const float4*)(bA + col);
    const float4 bb = *(const float4*)(bB + col);
    #pragma unroll
    for (int r = 0; r < 8; ++r) {
        const int row = row0 + rg * 8 + r;
        if (row < N) {
            float4 va = accA[r];
            va.x += ba.x; va.y += ba.y; va.z += ba.z; va.w += ba.w;
            float4 vb = accB[r];
            vb.x += bb.x; vb.y += bb.y; vb.z += bb.z; vb.w += bb.w;
            *(float4*)(Ah + (size_t)row * F + col) = va;
            *(float4*)(Bh + (size_t)row * F + col) = vb;
        }
    }
}

// ------- Kernel 2: Ce GEMM + e_ij + e_out + gated message + scatter-max -------
__global__ __launch_bounds__(NTHREADS)
void edge_kernel(const float* __restrict__ e,
                 const int* __restrict__ src, const int* __restrict__ dst,
                 const float* __restrict__ WC, const float* __restrict__ bC,
                 const float* __restrict__ Ah, const float* __restrict__ Bh,
                 float* __restrict__ e_out, unsigned int* __restrict__ cbuf, int E)
{
    __shared__ float xs[TILE_R][F];           // 32 KB edge-feature tile
    const int t = threadIdx.x;
    const int row0 = blockIdx.x * TILE_R;

    for (int i = t; i < TILE_R * (F / 4); i += NTHREADS) {
        const int r = i >> 5;
        const int c4 = i & 31;
        float4 v = make_float4(0.f, 0.f, 0.f, 0.f);
        if (row0 + r < E) v = ((const float4*)(e + (size_t)(row0 + r) * F))[c4];
        ((float4*)xs[r])[c4] = v;
    }
    __syncthreads();

    const int cg = t & 31, rg = t >> 5;
    const int col = cg * 4;
    float4 acc[8];
    #pragma unroll
    for (int r = 0; r < 8; ++r) acc[r] = make_float4(0.f, 0.f, 0.f, 0.f);

    for (int k = 0; k < F; k += 4) {
        float4 wc[4];
        #pragma unroll
        for (int i = 0; i < 4; ++i)
            wc[i] = *(const float4*)(WC + (size_t)(k + i) * F + col);
        #pragma unroll
        for (int r = 0; r < 8; ++r) {
            const float4 xv = *(const float4*)&xs[rg * 8 + r][k];
            fma_step(acc[r], xv, wc);
        }
    }

    const float4 bc = *(const float4*)(bC + col);
    #pragma unroll
    for (int r = 0; r < 8; ++r) {
        const int ed = row0 + rg * 8 + r;
        if (ed < E) {
            const int s = src[ed], d = dst[ed];
            const float4 bhs = *(const float4*)(Bh + (size_t)s * F + col);
            const float4 bhd = *(const float4*)(Bh + (size_t)d * F + col);
            const float4 ahs = *(const float4*)(Ah + (size_t)s * F + col);
            float4 eij;
            eij.x = acc[r].x + bc.x + bhs.x + bhd.x;
            eij.y = acc[r].y + bc.y + bhs.y + bhd.y;
            eij.z = acc[r].z + bc.z + bhs.z + bhd.z;
            eij.w = acc[r].w + bc.w + bhs.w + bhd.w;

            const float4 ein = *(const float4*)&xs[rg * 8 + r][col];
            float4 eo;
            eo.x = ein.x + fmaxf(eij.x, 0.f);
            eo.y = ein.y + fmaxf(eij.y, 0.f);
            eo.z = ein.z + fmaxf(eij.z, 0.f);
            eo.w = ein.w + fmaxf(eij.w, 0.f);
            *(float4*)(e_out + (size_t)ed * F + col) = eo;

            // m = relu(sigmoid(e_ij) * Ah[src]); ternary forces +0 so the
            // uint bit-pattern max stays monotone (avoid -0.0 = 0x80000000).
            float m0 = ahs.x / (1.f + __expf(-eij.x)); m0 = (m0 > 0.f) ? m0 : 0.f;
            float m1 = ahs.y / (1.f + __expf(-eij.y)); m1 = (m1 > 0.f) ? m1 : 0.f;
            float m2 = ahs.z / (1.f + __expf(-eij.z)); m2 = (m2 > 0.f) ? m2 : 0.f;
            float m3 = ahs.w / (1.f + __expf(-eij.w)); m3 = (m3 > 0.f) ? m3 : 0.f;

            // Test-and-test-and-set: cbuf starts at 0 and is monotonically
            // non-decreasing (all values >= +0, uint order == float order).
            // A stale read (non-coherent XCD L2) is always <= the true
            // running max, so skipping when m <= stale is safe; staleness
            // can only cause an extra atomic, never a wrong skip. This cuts
            // ~65M memory-side atomics to ~record-maxima only (~10M).
            unsigned int* cb = cbuf + (size_t)d * F + col;
            const uint4 cur = *(const uint4*)cb;
            const unsigned int u0 = __float_as_uint(m0);
            const unsigned int u1 = __float_as_uint(m1);
            const unsigned int u2 = __float_as_uint(m2);
            const unsigned int u3 = __float_as_uint(m3);
            if (u0 > cur.x) atomicMax(cb + 0, u0);
            if (u1 > cur.y) atomicMax(cb + 1, u1);
            if (u2 > cur.z) atomicMax(cb + 2, u2);
            if (u3 > cur.w) atomicMax(cb + 3, u3);
        }
    }
}

// ------- Kernel 3: bundle = [h,c]@Wap + bap; L2-normalize; relu; +h -------
__global__ __launch_bounds__(NTHREADS)
void apply_kernel(const float* __restrict__ h, const float* __restrict__ cbuf,
                  const float* __restrict__ Wap, const float* __restrict__ bap,
                  float* __restrict__ h_out, int N)
{
    __shared__ float xs[TILE_R][2 * F];       // 64 KB concat tile
    const int t = threadIdx.x;
    const int row0 = blockIdx.x * TILE_R;

    for (int i = t; i < TILE_R * (F / 4); i += NTHREADS) {
        const int r = i >> 5;
        const int c4 = i & 31;
        float4 hv = make_float4(0.f, 0.f, 0.f, 0.f);
        float4 cv = make_float4(0.f, 0.f, 0.f, 0.f);
        if (row0 + r < N) {
            hv = ((const float4*)(h + (size_t)(row0 + r) * F))[c4];
            cv = ((const float4*)(cbuf + (size_t)(row0 + r) * F))[c4];
        }
        ((float4*)xs[r])[c4] = hv;            // cols 0..127  : h
        ((float4*)xs[r])[c4 + 32] = cv;       // cols 128..255: c
    }
    __syncthreads();

    const int cg = t & 31, rg = t >> 5;
    const int col = cg * 4;
    float4 acc[8];
    #pragma unroll
    for (int r = 0; r < 8; ++r) acc[r] = make_float4(0.f, 0.f, 0.f, 0.f);

    for (int k = 0; k < 2 * F; k += 4) {
        float4 w[4];
        #pragma unroll
        for (int i = 0; i < 4; ++i)
            w[i] = *(const float4*)(Wap + (size_t)(k + i) * F + col);
        #pragma unroll
        for (int r = 0; r < 8; ++r) {
            const float4 xv = *(const float4*)&xs[rg * 8 + r][k];
            fma_step(acc[r], xv, w);
        }
    }

    const float4 bp = *(const float4*)(bap + col);
    #pragma unroll
    for (int r = 0; r < 8; ++r) {
        float4 a = acc[r];
        a.x += bp.x; a.y += bp.y; a.z += bp.z; a.w += bp.w;
        // row sum-of-squares: reduce over the 32 col-threads (half-wave)
        float ss = a.x * a.x + a.y * a.y + a.z * a.z + a.w * a.w;
        #pragma unroll
        for (int mm = 16; mm >= 1; mm >>= 1) ss += __shfl_xor(ss, mm, 64);
        const int row = row0 + rg * 8 + r;
        if (row < N) {
            const float dn = fmaxf(sqrtf(ss), 1e-12f);
            const float4 hv = *(const float4*)&xs[rg * 8 + r][col];
            float4 o;
            o.x = hv.x + fmaxf(a.x / dn, 0.f);
            o.y = hv.y + fmaxf(a.y / dn, 0.f);
            o.z = hv.z + fmaxf(a.z / dn, 0.f);
            o.w = hv.w + fmaxf(a.w / dn, 0.f);
            *(float4*)(h_out + (size_t)row * F + col) = o;
        }
    }
}

extern "C" void kernel_launch(void* const* d_in, const int* in_sizes, int n_in,
                              void* d_out, int out_size, void* d_ws, size_t ws_size,
                              hipStream_t stream)
{
    const float* h   = (const float*)d_in[0];
    const float* e   = (const float*)d_in[1];
    const int*   src = (const int*)d_in[2];
    const int*   dst = (const int*)d_in[3];
    const float* WA  = (const float*)d_in[4];
    const float* bA  = (const float*)d_in[5];
    const float* WB  = (const float*)d_in[6];
    const float* bB  = (const float*)d_in[7];
    const float* WC  = (const float*)d_in[8];
    const float* bC  = (const float*)d_in[9];
    const float* Wap = (const float*)d_in[10];
    const float* bap = (const float*)d_in[11];

    const int N = in_sizes[0] / F;
    const int E = in_sizes[2];

    float* Ah   = (float*)d_ws;                       // N*F
    float* Bh   = Ah + (size_t)N * F;                 // N*F
    float* cbuf = Bh + (size_t)N * F;                 // N*F (as uint bits)

    float* h_out = (float*)d_out;                     // N*F
    float* e_out = h_out + (size_t)N * F;             // E*F

    // segment-max identity: 0 bits == +0.0f (m >= 0 always; zero-degree -> 0)
    hipMemsetAsync(cbuf, 0, (size_t)N * F * sizeof(float), stream);

    const dim3 blk(NTHREADS);
    const int gn = (N + TILE_R - 1) / TILE_R;
    const int ge = (E + TILE_R - 1) / TILE_R;

    node_ab_kernel<<<gn, blk, 0, stream>>>(h, WA, bA, WB, bB, Ah, Bh, N);
    edge_kernel<<<ge, blk, 0, stream>>>(e, src, dst, WC, bC, Ah, Bh,
                                        e_out, (unsigned int*)cbuf, E);
    apply_kernel<<<gn, blk, 0, stream>>>(h, cbuf, Wap, bap, h_out, N);
}

// Round 4
// 990.199 us; speedup vs baseline: 1.2417x; 1.0042x over previous
//
#include <hip/hip_runtime.h>
#include <math.h>

#define F 128
#define C4 (F / 4)        // 32 float4 per F-row
#define TILE_R 64
#define TILE_AP 32
#define NTHREADS 256

// acc[c] += sum_i xv[i] * w[i][c]   (4 k-steps, 4 cols)
__device__ __forceinline__ void fma_step(float4& acc, const float4 xv, const float4* w) {
    acc.x = fmaf(xv.x, w[0].x, acc.x); acc.x = fmaf(xv.y, w[1].x, acc.x);
    acc.x = fmaf(xv.z, w[2].x, acc.x); acc.x = fmaf(xv.w, w[3].x, acc.x);
    acc.y = fmaf(xv.x, w[0].y, acc.y); acc.y = fmaf(xv.y, w[1].y, acc.y);
    acc.y = fmaf(xv.z, w[2].y, acc.y); acc.y = fmaf(xv.w, w[3].y, acc.y);
    acc.z = fmaf(xv.x, w[0].z, acc.z); acc.z = fmaf(xv.y, w[1].z, acc.z);
    acc.z = fmaf(xv.z, w[2].z, acc.z); acc.z = fmaf(xv.w, w[3].z, acc.z);
    acc.w = fmaf(xv.x, w[0].w, acc.w); acc.w = fmaf(xv.y, w[1].w, acc.w);
    acc.w = fmaf(xv.z, w[2].w, acc.w); acc.w = fmaf(xv.w, w[3].w, acc.w);
}

// ---- Kernel 1: AB[n][c4] = {Ah4, Bh4} interleaved (gather-line locality) ----
__global__ __launch_bounds__(NTHREADS)
void node_ab_kernel(const float* __restrict__ h,
                    const float* __restrict__ WA, const float* __restrict__ bA,
                    const float* __restrict__ WB, const float* __restrict__ bB,
                    float4* __restrict__ AB, int N)
{
    __shared__ float xs[TILE_R][F];           // 32 KB input tile
    const int t = threadIdx.x;
    const int row0 = blockIdx.x * TILE_R;

    for (int i = t; i < TILE_R * C4; i += NTHREADS) {
        const int r = i >> 5, c4 = i & 31;
        float4 v = make_float4(0.f, 0.f, 0.f, 0.f);
        if (row0 + r < N) v = ((const float4*)(h + (size_t)(row0 + r) * F))[c4];
        ((float4*)xs[r])[c4] = v;
    }
    __syncthreads();

    const int cg = t & 31, rg = t >> 5;
    const int col = cg * 4;
    float4 accA[8], accB[8];
    #pragma unroll
    for (int r = 0; r < 8; ++r) {
        accA[r] = make_float4(0.f, 0.f, 0.f, 0.f);
        accB[r] = make_float4(0.f, 0.f, 0.f, 0.f);
    }

    for (int k = 0; k < F; k += 4) {
        float4 wa[4], wb[4];
        #pragma unroll
        for (int i = 0; i < 4; ++i) {
            wa[i] = *(const float4*)(WA + (size_t)(k + i) * F + col);
            wb[i] = *(const float4*)(WB + (size_t)(k + i) * F + col);
        }
        #pragma unroll
        for (int r = 0; r < 8; ++r) {
            const float4 xv = *(const float4*)&xs[rg * 8 + r][k];
            fma_step(accA[r], xv, wa);
            fma_step(accB[r], xv, wb);
        }
    }

    const float4 ba = *(const float4*)(bA + col);
    const float4 bb = *(const float4*)(bB + col);
    #pragma unroll
    for (int r = 0; r < 8; ++r) {
        const int row = row0 + rg * 8 + r;
        if (row < N) {
            float4 va = accA[r];
            va.x += ba.x; va.y += ba.y; va.z += ba.z; va.w += ba.w;
            float4 vb = accB[r];
            vb.x += bb.x; vb.y += bb.y; vb.z += bb.z; vb.w += bb.w;
            float4* abp = AB + ((size_t)row * (2 * C4) + cg * 2);
            abp[0] = va;                      // A slice
            abp[1] = vb;                      // B slice, same 32B / cache line
        }
    }
}

// ------- Kernel 2: Ce GEMM + e_ij + e_out + gated message + scatter-max -------
template <bool FULL>
__global__ __launch_bounds__(NTHREADS)
void edge_kernel(const float* __restrict__ e,
                 const int* __restrict__ src, const int* __restrict__ dst,
                 const float* __restrict__ WC, const float* __restrict__ bC,
                 const float4* __restrict__ AB,
                 float* __restrict__ e_out, unsigned int* __restrict__ cbuf, int E)
{
    __shared__ float xs[TILE_R][F];           // 32 KB edge-feature tile
    const int t = threadIdx.x;
    const int row0 = blockIdx.x * TILE_R;

    for (int i = t; i < TILE_R * C4; i += NTHREADS) {
        const int r = i >> 5, c4 = i & 31;
        float4 v = make_float4(0.f, 0.f, 0.f, 0.f);
        if (FULL || row0 + r < E) v = ((const float4*)(e + (size_t)(row0 + r) * F))[c4];
        ((float4*)xs[r])[c4] = v;
    }
    __syncthreads();

    const int cg = t & 31, rg = t >> 5;
    const int col = cg * 4;
    float4 acc[8];
    #pragma unroll
    for (int r = 0; r < 8; ++r) acc[r] = make_float4(0.f, 0.f, 0.f, 0.f);

    for (int k = 0; k < F; k += 4) {
        float4 wc[4];
        #pragma unroll
        for (int i = 0; i < 4; ++i)
            wc[i] = *(const float4*)(WC + (size_t)(k + i) * F + col);
        #pragma unroll
        for (int r = 0; r < 8; ++r) {
            const float4 xv = *(const float4*)&xs[rg * 8 + r][k];
            fma_step(acc[r], xv, wc);
        }
    }

    const float4 bc = *(const float4*)(bC + col);
    const int ebase = row0 + rg * 8;

    // Phase 1: all indices up front (independent scalar-ish loads).
    int sx[8], dx[8];
    #pragma unroll
    for (int j = 0; j < 8; ++j) {
        const int ed = ebase + j;
        const bool ok = FULL || (ed < E);
        sx[j] = ok ? src[ed] : 0;
        dx[j] = ok ? dst[ed] : 0;
    }
    // Phase 2: ALL cbuf pre-reads hoisted above every atomic (same pointer as
    // the atomics, so the compiler could not hoist these itself). Stale reads
    // are safe: cbuf is monotone non-decreasing from 0.
    uint4 cur[8];
    #pragma unroll
    for (int j = 0; j < 8; ++j)
        cur[j] = *(const uint4*)(cbuf + (size_t)dx[j] * F + col);

    // Phase 3: gathers in batches of 4 rows (bounded VGPR, high MLP), then
    // compute + e_out store + test-and-test-and-set scatter max.
    #pragma unroll
    for (int rb = 0; rb < 2; ++rb) {
        float4 av[4], bs[4], bd[4];
        #pragma unroll
        for (int j = 0; j < 4; ++j) {
            const int s = sx[rb * 4 + j], d = dx[rb * 4 + j];
            const float4* p = AB + ((size_t)s * (2 * C4) + cg * 2);
            av[j] = p[0];                     // Ah[s] slice
            bs[j] = p[1];                     // Bh[s] slice (same cache line)
            bd[j] = AB[(size_t)d * (2 * C4) + cg * 2 + 1];  // Bh[d] slice
        }
        #pragma unroll
        for (int j = 0; j < 4; ++j) {
            const int r = rb * 4 + j;
            const int ed = ebase + r;
            if (!FULL && ed >= E) continue;
            float4 eij;
            eij.x = acc[r].x + bc.x + bs[j].x + bd[j].x;
            eij.y = acc[r].y + bc.y + bs[j].y + bd[j].y;
            eij.z = acc[r].z + bc.z + bs[j].z + bd[j].z;
            eij.w = acc[r].w + bc.w + bs[j].w + bd[j].w;

            const float4 ein = *(const float4*)&xs[rg * 8 + r][col];
            float4 eo;
            eo.x = ein.x + fmaxf(eij.x, 0.f);
            eo.y = ein.y + fmaxf(eij.y, 0.f);
            eo.z = ein.z + fmaxf(eij.z, 0.f);
            eo.w = ein.w + fmaxf(eij.w, 0.f);
            *(float4*)(e_out + (size_t)ed * F + col) = eo;

            // m = relu(sigmoid(e_ij)*Ah[src]); ternary forces +0 (never -0.0,
            // so uint bit order == float order on the monotone max).
            float m0 = av[j].x / (1.f + __expf(-eij.x)); m0 = (m0 > 0.f) ? m0 : 0.f;
            float m1 = av[j].y / (1.f + __expf(-eij.y)); m1 = (m1 > 0.f) ? m1 : 0.f;
            float m2 = av[j].z / (1.f + __expf(-eij.z)); m2 = (m2 > 0.f) ? m2 : 0.f;
            float m3 = av[j].w / (1.f + __expf(-eij.w)); m3 = (m3 > 0.f) ? m3 : 0.f;

            unsigned int* cb = cbuf + (size_t)dx[r] * F + col;
            const unsigned int u0 = __float_as_uint(m0);
            const unsigned int u1 = __float_as_uint(m1);
            const unsigned int u2 = __float_as_uint(m2);
            const unsigned int u3 = __float_as_uint(m3);
            if (u0 > cur[r].x) atomicMax(cb + 0, u0);
            if (u1 > cur[r].y) atomicMax(cb + 1, u1);
            if (u2 > cur[r].z) atomicMax(cb + 2, u2);
            if (u3 > cur[r].w) atomicMax(cb + 3, u3);
        }
    }
}

// ------- Kernel 3: bundle = [h,c]@Wap + bap; L2-normalize; relu; +h -------
// 32-row tile -> 32 KB LDS -> 5 blocks/CU (was 2 at 64 KB).
__global__ __launch_bounds__(NTHREADS)
void apply_kernel(const float* __restrict__ h, const float* __restrict__ cbuf,
                  const float* __restrict__ Wap, const float* __restrict__ bap,
                  float* __restrict__ h_out, int N)
{
    __shared__ float xs[TILE_AP][2 * F];      // 32 KB concat tile
    const int t = threadIdx.x;
    const int row0 = blockIdx.x * TILE_AP;

    for (int i = t; i < TILE_AP * 64; i += NTHREADS) {
        const int r = i >> 6, c4 = i & 63;
        const int row = row0 + r;
        float4 v = make_float4(0.f, 0.f, 0.f, 0.f);
        if (row < N)
            v = (c4 < 32) ? ((const float4*)(h + (size_t)row * F))[c4]
                          : ((const float4*)(cbuf + (size_t)row * F))[c4 - 32];
        ((float4*)xs[r])[c4] = v;
    }
    __syncthreads();

    const int cg = t & 31, rg = t >> 5;
    const int col = cg * 4;
    float4 acc[4];
    #pragma unroll
    for (int r = 0; r < 4; ++r) acc[r] = make_float4(0.f, 0.f, 0.f, 0.f);

    for (int k = 0; k < 2 * F; k += 4) {
        float4 w[4];
        #pragma unroll
        for (int i = 0; i < 4; ++i)
            w[i] = *(const float4*)(Wap + (size_t)(k + i) * F + col);
        #pragma unroll
        for (int r = 0; r < 4; ++r) {
            const float4 xv = *(const float4*)&xs[rg * 4 + r][k];
            fma_step(acc[r], xv, w);
        }
    }

    const float4 bp = *(const float4*)(bap + col);
    #pragma unroll
    for (int r = 0; r < 4; ++r) {
        float4 a = acc[r];
        a.x += bp.x; a.y += bp.y; a.z += bp.z; a.w += bp.w;
        float ss = a.x * a.x + a.y * a.y + a.z * a.z + a.w * a.w;
        #pragma unroll
        for (int mm = 16; mm >= 1; mm >>= 1) ss += __shfl_xor(ss, mm, 64);
        const int row = row0 + rg * 4 + r;
        if (row < N) {
            const float dn = fmaxf(sqrtf(ss), 1e-12f);
            const float4 hv = ((const float4*)xs[rg * 4 + r])[cg];
            float4 o;
            o.x = hv.x + fmaxf(a.x / dn, 0.f);
            o.y = hv.y + fmaxf(a.y / dn, 0.f);
            o.z = hv.z + fmaxf(a.z / dn, 0.f);
            o.w = hv.w + fmaxf(a.w / dn, 0.f);
            *(float4*)(h_out + (size_t)row * F + col) = o;
        }
    }
}

extern "C" void kernel_launch(void* const* d_in, const int* in_sizes, int n_in,
                              void* d_out, int out_size, void* d_ws, size_t ws_size,
                              hipStream_t stream)
{
    const float* h   = (const float*)d_in[0];
    const float* e   = (const float*)d_in[1];
    const int*   src = (const int*)d_in[2];
    const int*   dst = (const int*)d_in[3];
    const float* WA  = (const float*)d_in[4];
    const float* bA  = (const float*)d_in[5];
    const float* WB  = (const float*)d_in[6];
    const float* bB  = (const float*)d_in[7];
    const float* WC  = (const float*)d_in[8];
    const float* bC  = (const float*)d_in[9];
    const float* Wap = (const float*)d_in[10];
    const float* bap = (const float*)d_in[11];

    const int N = in_sizes[0] / F;
    const int E = in_sizes[2];

    float4* AB   = (float4*)d_ws;                         // N * 2F floats
    float*  cbuf = (float*)d_ws + (size_t)2 * N * F;      // N * F  (uint bits)

    float* h_out = (float*)d_out;                         // N*F
    float* e_out = h_out + (size_t)N * F;                 // E*F

    // segment-max identity: 0 bits == +0.0f (m >= 0 always; zero-degree -> 0)
    hipMemsetAsync(cbuf, 0, (size_t)N * F * sizeof(float), stream);

    const dim3 blk(NTHREADS);
    const int gn = (N + TILE_R - 1) / TILE_R;
    const int gap = (N + TILE_AP - 1) / TILE_AP;

    node_ab_kernel<<<gn, blk, 0, stream>>>(h, WA, bA, WB, bB, AB, N);
    if (E % TILE_R == 0) {
        edge_kernel<true><<<E / TILE_R, blk, 0, stream>>>(
            e, src, dst, WC, bC, AB, e_out, (unsigned int*)cbuf, E);
    } else {
        edge_kernel<false><<<(E + TILE_R - 1) / TILE_R, blk, 0, stream>>>(
            e, src, dst, WC, bC, AB, e_out, (unsigned int*)cbuf, E);
    }
    apply_kernel<<<gap, blk, 0, stream>>>(h, cbuf, Wap, bap, h_out, N);
}